// Round 6
// baseline (573.443 us; speedup 1.0000x reference)
//
#include <hip/hip_runtime.h>
#include <hip/hip_bf16.h>
#include <math.h>

constexpr int L_LEVELS = 16;
constexpr unsigned TABLE_SIZE = 1u << 19;
constexpr unsigned TMASK = TABLE_SIZE - 1u;
constexpr int N_PTS = 1048576;

typedef __bf16 bf16x8 __attribute__((ext_vector_type(8)));
typedef float f32x4 __attribute__((ext_vector_type(4)));

struct EncP {
    float scale[L_LEVELS];
    unsigned res[L_LEVELS];
};

struct alignas(8) f4_8 { float x, y, z, w; };

// ---------------------------------------------------------------------------
// Kernel 1: grid encode, one (point, level) per thread.
// R5 fix: the per-pair wrap BRANCH serialized the gathers (VGPR=16 -> ~1 load
// in flight/thread -> queue-depth-limited at ~0.2 lines/cy/CU). Now: compute
// all 4 pair indices, single rare wrap test, then 4 INDEPENDENT unconditional
// 16B loads batched back-to-back -> 4x outstanding misses per wave.
// Level-phased XCD-pinned blockIdx decode (proven: FETCH 3.1GB -> 0.34GB).
// ---------------------------------------------------------------------------
__global__ __launch_bounds__(256) void encode_kernel(
    const float* __restrict__ x,
    const float* __restrict__ table,
    unsigned* __restrict__ wsu,
    EncP p)
{
    const unsigned bid = blockIdx.x;
    const unsigned level = (bid & 7u) + 8u * (bid >> 15);
    const unsigned pblk  = (bid >> 3) & 4095u;
    const unsigned n = pblk * 256u + threadIdx.x;

    const float x0 = x[n * 3 + 0];
    const float x1 = x[n * 3 + 1];
    const float x2 = x[n * 3 + 2];

    const float s = p.scale[level];
    const unsigned r = p.res[level];
    const unsigned r2 = r * r;                   // uint32 wrap == int32 wrap bits

    float px = x0 * s + 0.5f;
    float py = x1 * s + 0.5f;
    float pz = x2 * s + 0.5f;
    float gx = floorf(px), gy = floorf(py), gz = floorf(pz);
    float fx = px - gx, fy = py - gy, fz = pz - gz;
    unsigned base = (unsigned)(int)gx + (unsigned)(int)gy * r + (unsigned)(int)gz * r2;

    const float* tl = table + (size_t)level * (size_t)TABLE_SIZE * 2u;

    // pair indices: cc -> (dy,dz) = (cc>>1, cc&1); dx=0/1 are adjacent entries
    const unsigned i0 = (base)           & TMASK;
    const unsigned i1 = (base + r2)      & TMASK;
    const unsigned i2 = (base + r)       & TMASK;
    const unsigned i3 = (base + r + r2)  & TMASK;
    const bool wrap = (i0 == TMASK) | (i1 == TMASK) | (i2 == TMASK) | (i3 == TMASK);

    f4_8 v0, v1, v2, v3;
    if (__builtin_expect(!wrap, 1)) {
        // 4 independent 16B gathers -> compiler batches, 4 in flight
        v0 = *(const f4_8*)(tl + 2u * i0);
        v1 = *(const f4_8*)(tl + 2u * i1);
        v2 = *(const f4_8*)(tl + 2u * i2);
        v3 = *(const f4_8*)(tl + 2u * i3);
    } else {
        // python mod wrap: (lin+1) % 2^19 == 0 ; ~1e-6 of lanes, exec-masked
        const float2 a0p = *(const float2*)(tl + 2u * i0);
        const float2 b0p = *(const float2*)(tl + 2u * ((i0 + 1u) & TMASK));
        v0.x = a0p.x; v0.y = a0p.y; v0.z = b0p.x; v0.w = b0p.y;
        const float2 a1p = *(const float2*)(tl + 2u * i1);
        const float2 b1p = *(const float2*)(tl + 2u * ((i1 + 1u) & TMASK));
        v1.x = a1p.x; v1.y = a1p.y; v1.z = b1p.x; v1.w = b1p.y;
        const float2 a2p = *(const float2*)(tl + 2u * i2);
        const float2 b2p = *(const float2*)(tl + 2u * ((i2 + 1u) & TMASK));
        v2.x = a2p.x; v2.y = a2p.y; v2.z = b2p.x; v2.w = b2p.y;
        const float2 a3p = *(const float2*)(tl + 2u * i3);
        const float2 b3p = *(const float2*)(tl + 2u * ((i3 + 1u) & TMASK));
        v3.x = a3p.x; v3.y = a3p.y; v3.z = b3p.x; v3.w = b3p.y;
    }

    const float fx1 = 1.f - fx, fy1 = 1.f - fy, fz1 = 1.f - fz;
    float a0 = 0.f, a1 = 0.f;
#define CORNER_PAIR(vv, wyz)                              \
    {                                                     \
        const float m0 = fmaf(fx, (vv).z, fx1 * (vv).x);  \
        const float m1 = fmaf(fx, (vv).w, fx1 * (vv).y);  \
        a0 = fmaf((wyz), m0, a0);                         \
        a1 = fmaf((wyz), m1, a1);                         \
    }
    CORNER_PAIR(v0, fy1 * fz1)   // dy=0,dz=0
    CORNER_PAIR(v1, fy1 * fz)    // dy=0,dz=1
    CORNER_PAIR(v2, fy  * fz1)   // dy=1,dz=0
    CORNER_PAIR(v3, fy  * fz)    // dy=1,dz=1
#undef CORNER_PAIR

    __hip_bfloat162 hv = __float22bfloat162_rn(make_float2(a0, a1));
    unsigned u;
    __builtin_memcpy(&u, &hv, 4);
    wsu[(size_t)level * N_PTS + n] = u;   // coalesced u32
}

// ---------------------------------------------------------------------------
// Kernel 2: MFMA MLP 32->64->64->32 (bf16 in, fp32 accum). Proven R5: ~29us.
// ---------------------------------------------------------------------------
__global__ __launch_bounds__(256) void mlp_mfma_kernel(
    const unsigned* __restrict__ wsu,
    const float* __restrict__ W1,
    const float* __restrict__ W2,
    const float* __restrict__ W3,
    float* __restrict__ out)
{
    __shared__ __align__(16) unsigned short xin[64 * 40];   // [pt][feat] pad 40
    __shared__ __align__(16) unsigned short H1[64 * 72];    // [pt][feat] pad 72
    __shared__ __align__(16) unsigned short H2[64 * 72];

    const int tid = threadIdx.x;
    const int l  = tid & 63;
    const int w  = tid >> 6;
    const int lr = l & 15;    // frag row (A) / col (B,D)
    const int lg = l >> 4;    // k-group

    bf16x8 b1[4], b2[4][2], b3[2][2];
#pragma unroll
    for (int cb = 0; cb < 4; ++cb)
#pragma unroll
        for (int e = 0; e < 8; ++e)
            b1[cb][e] = (__bf16)W1[(lg * 8 + e) * 64 + cb * 16 + lr];
#pragma unroll
    for (int cb = 0; cb < 4; ++cb)
#pragma unroll
        for (int kh = 0; kh < 2; ++kh)
#pragma unroll
            for (int e = 0; e < 8; ++e)
                b2[cb][kh][e] = (__bf16)W2[(kh * 32 + lg * 8 + e) * 64 + cb * 16 + lr];
#pragma unroll
    for (int cb = 0; cb < 2; ++cb)
#pragma unroll
        for (int kh = 0; kh < 2; ++kh)
#pragma unroll
            for (int e = 0; e < 8; ++e)
                b3[cb][kh][e] = (__bf16)W3[(kh * 32 + lg * 8 + e) * 32 + cb * 16 + lr];

    constexpr int ITERS = 8;
    const int tile0 = blockIdx.x * ITERS;
    const f32x4 z = {0.f, 0.f, 0.f, 0.f};

    for (int it = 0; it < ITERS; ++it) {
        const int p0 = (tile0 + it) * 64;

        {
            const int i  = tid & 63;
            const int lb = tid >> 6;
#pragma unroll
            for (int ps = 0; ps < 4; ++ps) {
                const int lev = ps * 4 + lb;
                const unsigned v = wsu[(size_t)lev * N_PTS + p0 + i];
                *(unsigned*)&xin[i * 40 + 2 * lev] = v;
            }
        }
        __syncthreads();

        const int row = w * 16 + lr;

        const bf16x8 a1 = *(const bf16x8*)&xin[row * 40 + lg * 8];
        f32x4 d1[4];
#pragma unroll
        for (int cb = 0; cb < 4; ++cb)
            d1[cb] = __builtin_amdgcn_mfma_f32_16x16x32_bf16(a1, b1[cb], z, 0, 0, 0);
#pragma unroll
        for (int cb = 0; cb < 4; ++cb)
#pragma unroll
            for (int reg = 0; reg < 4; ++reg) {
                const __bf16 hv = (__bf16)fmaxf(d1[cb][reg], 0.f);
                unsigned short bits;
                __builtin_memcpy(&bits, &hv, 2);
                H1[(w * 16 + lg * 4 + reg) * 72 + cb * 16 + lr] = bits;
            }

        const bf16x8 a2_0 = *(const bf16x8*)&H1[row * 72 + lg * 8];
        const bf16x8 a2_1 = *(const bf16x8*)&H1[row * 72 + 32 + lg * 8];
        f32x4 d2[4];
#pragma unroll
        for (int cb = 0; cb < 4; ++cb) {
            f32x4 t = __builtin_amdgcn_mfma_f32_16x16x32_bf16(a2_0, b2[cb][0], z, 0, 0, 0);
            d2[cb]  = __builtin_amdgcn_mfma_f32_16x16x32_bf16(a2_1, b2[cb][1], t, 0, 0, 0);
        }
#pragma unroll
        for (int cb = 0; cb < 4; ++cb)
#pragma unroll
            for (int reg = 0; reg < 4; ++reg) {
                const __bf16 hv = (__bf16)fmaxf(d2[cb][reg], 0.f);
                unsigned short bits;
                __builtin_memcpy(&bits, &hv, 2);
                H2[(w * 16 + lg * 4 + reg) * 72 + cb * 16 + lr] = bits;
            }

        const bf16x8 a3_0 = *(const bf16x8*)&H2[row * 72 + lg * 8];
        const bf16x8 a3_1 = *(const bf16x8*)&H2[row * 72 + 32 + lg * 8];
        f32x4 d3[2];
#pragma unroll
        for (int cb = 0; cb < 2; ++cb) {
            f32x4 t = __builtin_amdgcn_mfma_f32_16x16x32_bf16(a3_0, b3[cb][0], z, 0, 0, 0);
            d3[cb]  = __builtin_amdgcn_mfma_f32_16x16x32_bf16(a3_1, b3[cb][1], t, 0, 0, 0);
        }

        float* ob = out + ((size_t)p0 + w * 16) * 32;
#pragma unroll
        for (int cb = 0; cb < 2; ++cb)
#pragma unroll
            for (int reg = 0; reg < 4; ++reg)
                ob[(lg * 4 + reg) * 32 + cb * 16 + lr] = fmaxf(d3[cb][reg], 0.f);

        __syncthreads();
    }
}

// ---------------------------------------------------------------------------
// Fallback: monolithic fp32 kernel (used only if ws too small).
// ---------------------------------------------------------------------------
__global__ __launch_bounds__(256) void mono_kernel(
    const float* __restrict__ x, const float* __restrict__ table,
    const float* __restrict__ W1, const float* __restrict__ W2,
    const float* __restrict__ W3, float* __restrict__ out, EncP p)
{
    __shared__ float lds[256 * 33];
    const int tid = threadIdx.x;
    const int n = blockIdx.x * 256 + tid;
    const float x0 = x[n * 3 + 0], x1 = x[n * 3 + 1], x2 = x[n * 3 + 2];
    float xc[32];
#pragma unroll
    for (int l = 0; l < L_LEVELS; ++l) {
        const float s = p.scale[l];
        const unsigned r = p.res[l], r2 = r * r;
        float px = x0 * s + 0.5f, py = x1 * s + 0.5f, pz = x2 * s + 0.5f;
        float gx = floorf(px), gy = floorf(py), gz = floorf(pz);
        float fx = px - gx, fy = py - gy, fz = pz - gz;
        unsigned base = (unsigned)(int)gx + (unsigned)(int)gy * r + (unsigned)(int)gz * r2;
        const float* tl = table + (size_t)l * (size_t)TABLE_SIZE * 2u;
        float a0 = 0.f, a1 = 0.f;
#pragma unroll
        for (int c = 0; c < 8; ++c) {
            const unsigned dx = (c >> 2) & 1u, dy = (c >> 1) & 1u, dz = c & 1u;
            unsigned idx = (base + dx + dy * r + dz * r2) & TMASK;
            const float2 f = *(const float2*)(tl + 2u * idx);
            const float w = (dx ? fx : 1.f - fx) * (dy ? fy : 1.f - fy) * (dz ? fz : 1.f - fz);
            a0 += w * f.x; a1 += w * f.y;
        }
        xc[2 * l] = a0; xc[2 * l + 1] = a1;
    }
    float h1[64];
#pragma unroll
    for (int j = 0; j < 64; ++j) h1[j] = 0.f;
#pragma unroll
    for (int i = 0; i < 32; ++i) {
        const float v = xc[i];
#pragma unroll
        for (int j = 0; j < 64; ++j) h1[j] = fmaf(v, W1[i * 64 + j], h1[j]);
    }
#pragma unroll
    for (int j = 0; j < 64; ++j) h1[j] = fmaxf(h1[j], 0.f);
    float h2[64];
#pragma unroll
    for (int j = 0; j < 64; ++j) h2[j] = 0.f;
#pragma unroll
    for (int i = 0; i < 64; ++i) {
        const float v = h1[i];
#pragma unroll
        for (int j = 0; j < 64; ++j) h2[j] = fmaf(v, W2[i * 64 + j], h2[j]);
    }
#pragma unroll
    for (int j = 0; j < 64; ++j) h2[j] = fmaxf(h2[j], 0.f);
    float o[32];
#pragma unroll
    for (int j = 0; j < 32; ++j) o[j] = 0.f;
#pragma unroll
    for (int i = 0; i < 64; ++i) {
        const float v = h2[i];
#pragma unroll
        for (int j = 0; j < 32; ++j) o[j] = fmaf(v, W3[i * 32 + j], o[j]);
    }
#pragma unroll
    for (int j = 0; j < 32; ++j) lds[tid * 33 + j] = fmaxf(o[j], 0.f);
    __syncthreads();
    float* outb = out + (size_t)blockIdx.x * 8192;
#pragma unroll
    for (int k = 0; k < 8; ++k) {
        const int e = k * 1024 + tid * 4;
        float4 v;
        v.x = lds[((e + 0) >> 5) * 33 + ((e + 0) & 31)];
        v.y = lds[((e + 1) >> 5) * 33 + ((e + 1) & 31)];
        v.z = lds[((e + 2) >> 5) * 33 + ((e + 2) & 31)];
        v.w = lds[((e + 3) >> 5) * 33 + ((e + 3) & 31)];
        *(float4*)(outb + e) = v;
    }
}

extern "C" void kernel_launch(void* const* d_in, const int* in_sizes, int n_in,
                              void* d_out, int out_size, void* d_ws, size_t ws_size,
                              hipStream_t stream) {
    (void)in_sizes; (void)n_in; (void)out_size;

    const float* x     = (const float*)d_in[0];
    const float* table = (const float*)d_in[2];
    const float* W1    = (const float*)d_in[3];
    const float* W2    = (const float*)d_in[4];
    const float* W3    = (const float*)d_in[5];
    float* out = (float*)d_out;

    EncP p;
    const double b = exp(log(2048.0 / 16.0) / 15.0);
    for (int l = 0; l < L_LEVELS; ++l) {
        const float s = (float)(16.0 * pow(b, (double)l) - 1.0);
        p.scale[l] = s;
        p.res[l] = (unsigned)((long long)s) + 1u;
    }

    const size_t ws_needed = (size_t)L_LEVELS * N_PTS * sizeof(unsigned); // 64 MB
    if (ws_size >= ws_needed) {
        unsigned* wsu = (unsigned*)d_ws;
        hipLaunchKernelGGL(encode_kernel, dim3(65536), dim3(256), 0, stream,
                           x, table, wsu, p);
        hipLaunchKernelGGL(mlp_mfma_kernel, dim3(2048), dim3(256), 0, stream,
                           wsu, W1, W2, W3, out);
    } else {
        hipLaunchKernelGGL(mono_kernel, dim3(N_PTS / 256), dim3(256), 0, stream,
                           x, table, W1, W2, W3, out, p);
    }
}